// Round 14
// baseline (134.056 us; speedup 1.0000x reference)
//
#include <hip/hip_runtime.h>

// ---------- types ----------
typedef __bf16 bf16x8 __attribute__((ext_vector_type(8)));
typedef float f32x4 __attribute__((ext_vector_type(4)));
typedef float f32x16 __attribute__((ext_vector_type(16)));

__device__ __forceinline__ unsigned short f2bf(float f) {
    return __builtin_bit_cast(unsigned short, (__bf16)f);
}

__device__ __forceinline__ float bf2f(unsigned short u) {
    unsigned int x = ((unsigned int)u) << 16;
    return __builtin_bit_cast(float, x);
}

__device__ __forceinline__ unsigned int packbf2(float a, float b) {
    unsigned short lo = f2bf(a), hi = f2bf(b);
    return (unsigned int)lo | ((unsigned int)hi << 16);
}

__device__ __forceinline__ bf16x8 load_frag(const unsigned short* p) {
    int4 v = *reinterpret_cast<const int4*>(p);
    return __builtin_bit_cast(bf16x8, v);
}

__device__ __forceinline__ void gload_lds16(const unsigned short* g, unsigned short* l) {
    __builtin_amdgcn_global_load_lds((const __attribute__((address_space(1))) void*)g,
                                     (__attribute__((address_space(3))) void*)l, 16, 0, 0);
}

// ---------- prep: x + 4 weights -> bf16 (4 elems/thread); tail blocks build rope table ----------
__global__ __launch_bounds__(256) void prep_bf16(const float* __restrict__ x,
                                                 const float* __restrict__ wq,
                                                 const float* __restrict__ wk,
                                                 const float* __restrict__ wv,
                                                 const float* __restrict__ wp,
                                                 unsigned short* __restrict__ xb,
                                                 unsigned short* __restrict__ wall,
                                                 float* __restrict__ cost,
                                                 float* __restrict__ sint) {
    int bid = blockIdx.x;
    if (bid < 8192) {
        int i = (bid * 256 + threadIdx.x) * 4;            // 0..8M-4
        const float* src;
        unsigned short* dst;
        int soff, doff;
        if (i < (1 << 22)) {                               // x: 4M elems
            src = x; dst = xb; soff = i; doff = i;
        } else {
            int j = i - (1 << 22);                         // weights: 4x 1M elems
            int r = j >> 20;
            src = (r == 0) ? wq : ((r == 1) ? wk : ((r == 2) ? wv : wp));
            dst = wall; soff = j & 1048575; doff = j;
        }
        float4 v = *reinterpret_cast<const float4*>(&src[soff]);
        unsigned short tmp[4] = {f2bf(v.x), f2bf(v.y), f2bf(v.z), f2bf(v.w)};
        *reinterpret_cast<int2*>(&dst[doff]) = *reinterpret_cast<int2*>(tmp);
    } else {
        int i = (bid - 8192) * 256 + threadIdx.x;          // 2048*32
        int t = i >> 5, d = i & 31;
        float inv = powf(10000.0f, -(float)d / 32.0f);
        float f = (float)t * inv;
        cost[i] = cosf(f);
        sint[i] = sinf(f);
    }
}

// ---------- GEMM: C[M,N] = A[M,K] @ B[N,K]^T  (bf16 in; bf16 out) ----------
// global_load_lds (width 16) into LINEAR LDS [128][64] with both-sides XOR swizzle (proven R9).
__global__ __launch_bounds__(256) void gemm_bf16(const unsigned short* __restrict__ A,
                                                 const unsigned short* __restrict__ B,
                                                 unsigned short* __restrict__ C,
                                                 int N, int K) {
    __shared__ __align__(16) unsigned short As[128 * 64];
    __shared__ __align__(16) unsigned short Bs[128 * 64];
    int tid = threadIdx.x;
    int lane = tid & 63;
    int w = tid >> 6;
    int wm = w >> 1, wn = w & 1;
    int m0 = blockIdx.x * 128;
    int n0 = blockIdx.y * 128;

    f32x4 acc[4][4] = {};

    int r8 = lane >> 3;              // 0..7: row within 8-row stripe
    int csrc = (lane & 7) ^ r8;      // pre-swizzled source 16B-unit (involution)

    for (int k0 = 0; k0 < K; k0 += 64) {
        __syncthreads();
#pragma unroll
        for (int c = 0; c < 4; ++c) {
            int row = 32 * w + 8 * c + r8;
            gload_lds16(&A[(size_t)(m0 + row) * K + k0 + csrc * 8], &As[(32 * w + 8 * c) * 64]);
            gload_lds16(&B[(size_t)(n0 + row) * K + k0 + csrc * 8], &Bs[(32 * w + 8 * c) * 64]);
        }
        __syncthreads();   // compiler drains vmcnt before s_barrier -> LDS consistent
#pragma unroll
        for (int kk = 0; kk < 2; ++kk) {
            int col16 = kk * 4 + (lane >> 4);
            bf16x8 af[4], bfr[4];
#pragma unroll
            for (int i = 0; i < 4; ++i) {
                int row = wm * 64 + i * 16 + (lane & 15);
                af[i] = load_frag(&As[row * 64 + (col16 ^ (row & 7)) * 8]);
            }
#pragma unroll
            for (int j = 0; j < 4; ++j) {
                int row = wn * 64 + j * 16 + (lane & 15);
                bfr[j] = load_frag(&Bs[row * 64 + (col16 ^ (row & 7)) * 8]);
            }
#pragma unroll
            for (int i = 0; i < 4; ++i)
#pragma unroll
                for (int j = 0; j < 4; ++j)
                    acc[i][j] = __builtin_amdgcn_mfma_f32_16x16x32_bf16(af[i], bfr[j], acc[i][j], 0, 0, 0);
        }
    }
    int r0 = (lane >> 4) * 4;
    int cc = lane & 15;
#pragma unroll
    for (int i = 0; i < 4; ++i)
#pragma unroll
        for (int j = 0; j < 4; ++j)
#pragma unroll
            for (int r = 0; r < 4; ++r) {
                size_t m = m0 + wm * 64 + i * 16 + r0 + r;
                size_t n = n0 + wn * 64 + j * 16 + cc;
                C[m * N + n] = f2bf(acc[i][j][r]);
            }
}

// ---------- proj GEMM with fused kv-split combine on the A side ----------
// A[m][k] = (pO_ck0 + pO_ck1)[bh(m,k)][q(m)][d(k)] / (l0+l1); B = wproj; C fp32.
__global__ __launch_bounds__(256) void gemm_proj(const unsigned short* __restrict__ pO,
                                                 const float* __restrict__ lsum,
                                                 const unsigned short* __restrict__ B,
                                                 float* __restrict__ C) {
    __shared__ __align__(16) unsigned short As[128 * 64];
    __shared__ __align__(16) unsigned short Bs[128 * 64];
    int tid = threadIdx.x;
    int lane = tid & 63;
    int w = tid >> 6;
    int wm = w >> 1, wn = w & 1;
    int m0 = blockIdx.x * 128;
    int n0 = blockIdx.y * 128;

    f32x4 acc[4][4] = {};

    int r8 = lane >> 3;              // 0..7
    int c8 = lane & 7;               // 0..7: LDS slot this thread fills
    int csrc = c8 ^ r8;              // global 16B-unit it loads (involution)

    for (int k0 = 0; k0 < 1024; k0 += 64) {
        int h = k0 >> 6;
        __syncthreads();
#pragma unroll
        for (int c = 0; c < 4; ++c) {
            int row = 32 * w + 8 * c + r8;
            int m = m0 + row;
            int bh = ((m >> 11) << 4) + h;
            int qi = m & 2047;
            int li = bh * 2048 + qi;
            size_t pi = (size_t)li * 64 + csrc * 8;
            int4 p0 = *reinterpret_cast<const int4*>(&pO[pi]);
            int4 p1 = *reinterpret_cast<const int4*>(&pO[4194304u + pi]);
            float linv = 1.0f / (lsum[li] + lsum[65536 + li]);
            const unsigned short* u0 = reinterpret_cast<const unsigned short*>(&p0);
            const unsigned short* u1 = reinterpret_cast<const unsigned short*>(&p1);
            unsigned short tmp[8];
#pragma unroll
            for (int j = 0; j < 8; ++j) tmp[j] = f2bf((bf2f(u0[j]) + bf2f(u1[j])) * linv);
            *reinterpret_cast<int4*>(&As[row * 64 + c8 * 8]) = *reinterpret_cast<int4*>(tmp);
            gload_lds16(&B[(size_t)(n0 + row) * 1024 + k0 + csrc * 8], &Bs[(32 * w + 8 * c) * 64]);
        }
        __syncthreads();
#pragma unroll
        for (int kk = 0; kk < 2; ++kk) {
            int col16 = kk * 4 + (lane >> 4);
            bf16x8 af[4], bfr[4];
#pragma unroll
            for (int i = 0; i < 4; ++i) {
                int row = wm * 64 + i * 16 + (lane & 15);
                af[i] = load_frag(&As[row * 64 + (col16 ^ (row & 7)) * 8]);
            }
#pragma unroll
            for (int j = 0; j < 4; ++j) {
                int row = wn * 64 + j * 16 + (lane & 15);
                bfr[j] = load_frag(&Bs[row * 64 + (col16 ^ (row & 7)) * 8]);
            }
#pragma unroll
            for (int i = 0; i < 4; ++i)
#pragma unroll
                for (int j = 0; j < 4; ++j)
                    acc[i][j] = __builtin_amdgcn_mfma_f32_16x16x32_bf16(af[i], bfr[j], acc[i][j], 0, 0, 0);
        }
    }
    int r0 = (lane >> 4) * 4;
    int cc = lane & 15;
#pragma unroll
    for (int i = 0; i < 4; ++i)
#pragma unroll
        for (int j = 0; j < 4; ++j)
#pragma unroll
            for (int r = 0; r < 4; ++r) {
                size_t m = m0 + wm * 64 + i * 16 + r0 + r;
                size_t n = n0 + wn * 64 + j * 16 + cc;
                C[m * 1024 + n] = acc[i][j][r];
            }
}

// ---------- fused: rmsnorm+rope for q,k (blocks <16384) | v-lerp+transpose+v1-out (rest) ----------
__global__ __launch_bounds__(256) void post_lerp(const unsigned short* __restrict__ qkv, // bf16 [4096][3072]
                                                 const float* __restrict__ cost,
                                                 const float* __restrict__ sint,
                                                 const float* __restrict__ v1,
                                                 const float* __restrict__ lamb_p,
                                                 unsigned short* __restrict__ qb,
                                                 unsigned short* __restrict__ kb,
                                                 unsigned short* __restrict__ vt,
                                                 float* __restrict__ outv1) {
    __shared__ __align__(16) unsigned short tile[64][72];
    int bid = blockIdx.x;
    if (bid < 16384) {
        int gid = bid * 4 + (threadIdx.x >> 6);   // (b,t,h) row id, 0..65535
        int lane = threadIdx.x & 63;
        int h = gid & 15;
        int t = (gid >> 4) & 2047;
        int b = gid >> 15;
        int m = b * 2048 + t;

        float q = bf2f(qkv[(size_t)m * 3072 + h * 64 + lane]);
        float k = bf2f(qkv[(size_t)m * 3072 + 1024 + h * 64 + lane]);

        float sq = q * q, sk = k * k;
        for (int msk = 1; msk < 64; msk <<= 1) {
            sq += __shfl_xor(sq, msk, 64);
            sk += __shfl_xor(sk, msk, 64);
        }
        q *= rsqrtf(sq * (1.0f / 64.0f) + 1e-6f);
        k *= rsqrtf(sk * (1.0f / 64.0f) + 1e-6f);

        int d = lane & 31;
        float c = cost[t * 32 + d], s = sint[t * 32 + d];
        float qp = __shfl_xor(q, 32, 64);
        float kp = __shfl_xor(k, 32, 64);
        float qo = (lane < 32) ? (q * c + qp * s) : (q * c - qp * s);
        float ko = (lane < 32) ? (k * c + kp * s) : (k * c - kp * s);
        qo *= 0.125f * 1.44269504088896f;   // fold softmax scale AND log2(e): attn uses exp2

        size_t oidx = ((size_t)((b * 16 + h) * 2048 + t)) * 64 + lane;
        qb[oidx] = f2bf(qo);
        kb[oidx] = f2bf(ko);
    } else {
        int b2 = bid - 16384;            // 0..1023
        int bh = b2 >> 5;
        int b = bh >> 4, h = bh & 15;
        int t0 = (b2 & 31) * 64;
        int tid = threadIdx.x;
        int r = tid >> 3;            // 0..31
        int c = (tid & 7) * 8;       // 0..56
        float lamb = lamb_p[0];
        float oml = 1.0f - lamb;

#pragma unroll
        for (int half = 0; half < 2; ++half) {
            int row = r + half * 32;
            int m = b * 2048 + t0 + row;
            int4 vv = *reinterpret_cast<const int4*>(&qkv[(size_t)m * 3072 + 2048 + h * 64 + c]);
            const unsigned short* vs = reinterpret_cast<const unsigned short*>(&vv);
            size_t v1i = ((size_t)m * 16 + h) * 64 + c;
            float4 va = *reinterpret_cast<const float4*>(&v1[v1i]);
            float4 vb4 = *reinterpret_cast<const float4*>(&v1[v1i + 4]);
            *reinterpret_cast<float4*>(&outv1[v1i]) = va;          // v1 passthrough output
            *reinterpret_cast<float4*>(&outv1[v1i + 4]) = vb4;
            float v1a[8] = {va.x, va.y, va.z, va.w, vb4.x, vb4.y, vb4.z, vb4.w};
            unsigned short tmp[8];
#pragma unroll
            for (int j = 0; j < 8; ++j) tmp[j] = f2bf(oml * bf2f(vs[j]) + lamb * v1a[j]);
            *reinterpret_cast<int4*>(&tile[row][c]) = *reinterpret_cast<int4*>(tmp);
        }
        __syncthreads();
        unsigned short* dst = vt + (size_t)bh * 64 * 2048 + t0;
        unsigned short tmp[8];
#pragma unroll
        for (int j = 0; j < 8; ++j) tmp[j] = tile[c + j][r];
        *reinterpret_cast<int4*>(&dst[(size_t)r * 2048 + c]) = *reinterpret_cast<int4*>(tmp);
#pragma unroll
        for (int j = 0; j < 8; ++j) tmp[j] = tile[c + j][r + 32];
        *reinterpret_cast<int4*>(&dst[(size_t)(r + 32) * 2048 + c]) = *reinterpret_cast<int4*>(tmp);
    }
}

// ---------- flash attention, kv-split x2, causal, swapped-QK^T 32x32 MFMA ----------
// R13 body; chunk0 = kt in [0,qt], chunk1 = [qt+1,2qt+1] (both qt+1 tiles, balanced).
__global__ __launch_bounds__(256) void attn(const unsigned short* __restrict__ qb,
                                            const unsigned short* __restrict__ kb,
                                            const unsigned short* __restrict__ vt,   // [bh][64][2048]
                                            unsigned short* __restrict__ pO,         // [ck][bh][2048][64] bf16
                                            float* __restrict__ lsum) {              // [ck][bh][2048] f32
    __shared__ __align__(16) unsigned short Ks[64][72];   // [kv][d]
    __shared__ __align__(16) unsigned short Vt[64][72];   // [d][kv]
    int tid = threadIdx.x;
    int lane = tid & 63;
    int w = tid >> 6;
    int hi = lane >> 5;
    int l31 = lane & 31;

    int bid = blockIdx.x;                    // 0..1023
    int bh = bid & 31;
    int r5 = bid >> 5;                       // 0..31
    int qt = 15 - (r5 >> 1);                 // heavy first
    int ck = r5 & 1;
    int q0 = qt * 128;
    const size_t base = (size_t)bh * 2048 * 64;
    const unsigned short* vtb = vt + (size_t)bh * 64 * 2048;
    int ktlo = ck * (qt + 1);
    int kthi = (ck + 1) * (qt + 1);          // exclusive

    bf16x8 qf[4];
    int qrow = q0 + w * 32 + l31;
#pragma unroll
    for (int kd = 0; kd < 4; ++kd)
        qf[kd] = load_frag(&qb[base + (size_t)qrow * 64 + kd * 16 + hi * 8]);

    f32x16 oacc[2] = {};
    float lrun = 0.0f;

    int srow = tid >> 3;            // 0..31
    int scol = (tid & 7) * 8;       // 0..56
    int4 kr0, kr1, vr0, vr1;
#define LOADT(kt_)                                                                                    \
    do {                                                                                              \
        kr0 = *reinterpret_cast<const int4*>(&kb[base + (size_t)((kt_)*64 + srow) * 64 + scol]);      \
        kr1 = *reinterpret_cast<const int4*>(&kb[base + (size_t)((kt_)*64 + srow + 32) * 64 + scol]); \
        vr0 = *reinterpret_cast<const int4*>(&vtb[(size_t)srow * 2048 + (kt_)*64 + scol]);            \
        vr1 = *reinterpret_cast<const int4*>(&vtb[(size_t)(srow + 32) * 2048 + (kt_)*64 + scol]);     \
    } while (0)

    int qwlo = q0 + w * 32;
    {
        LOADT(ktlo);
        for (int kt = ktlo; kt < kthi; ++kt) {
            __syncthreads();
            *reinterpret_cast<int4*>(&Ks[srow][scol]) = kr0;
            *reinterpret_cast<int4*>(&Ks[srow + 32][scol]) = kr1;
            *reinterpret_cast<int4*>(&Vt[srow][scol]) = vr0;
            *reinterpret_cast<int4*>(&Vt[srow + 32][scol]) = vr1;
            __syncthreads();
            if (kt + 1 < kthi) LOADT(kt + 1);

            if (kt * 64 <= qwlo + 31) {
                bool diag = (kt * 64 + 63 > qwlo);
                float rs01 = 0.0f, rs23 = 0.0f;
#pragma unroll
                for (int ntl = 0; ntl < 2; ++ntl) {
                    // QK^T for this 32-kv half: m = kv, n = q
                    f32x16 sacc = {};
#pragma unroll
                    for (int kd = 0; kd < 4; ++kd) {
                        bf16x8 kf = load_frag(&Ks[ntl * 32 + l31][kd * 16 + hi * 8]);
                        sacc = __builtin_amdgcn_mfma_f32_32x32x16_bf16(kf, qf[kd], sacc, 0, 0, 0);
                    }

#pragma unroll
                    for (int r = 0; r < 16; ++r) {
                        float s = sacc[r];
                        if (diag) {
                            int kvg = kt * 64 + ntl * 32 + (r & 3) + 8 * (r >> 2) + 4 * hi;
                            if (kvg > qrow) s = -3.0e38f;
                        }
                        float e = __builtin_amdgcn_exp2f(s);
                        sacc[r] = e;
                        if (r & 2) rs23 += e; else rs01 += e;
                    }

                    unsigned int wAa[4], wBb[4];
#pragma unroll
                    for (int rr = 0; rr < 4; ++rr) {
                        wAa[rr] = packbf2(sacc[4 * rr + 0], sacc[4 * rr + 1]);
                        wBb[rr] = packbf2(sacc[4 * rr + 2], sacc[4 * rr + 3]);
                    }

                    // PV for this half: 2 k-slices of 16 kv; A-frag via permlane32_swap
#pragma unroll
                    for (int ks2 = 0; ks2 < 2; ++ks2) {
                        int b2 = ks2 * 2;
                        auto rA = __builtin_amdgcn_permlane32_swap(wAa[b2], wAa[b2 + 1], false, false);
                        auto rB = __builtin_amdgcn_permlane32_swap(wBb[b2], wBb[b2 + 1], false, false);
                        uint4 pa;
                        pa.x = rA[0];   // kv 16ks+8hi+{0,1}
                        pa.y = rB[0];   // +{2,3}
                        pa.z = rA[1];   // +{4,5}
                        pa.w = rB[1];   // +{6,7}
                        bf16x8 paf = __builtin_bit_cast(bf16x8, pa);
                        int ks = ntl * 2 + ks2;
#pragma unroll
                        for (int dt = 0; dt < 2; ++dt) {
                            bf16x8 vtf = load_frag(&Vt[dt * 32 + l31][ks * 16 + hi * 8]);
                            oacc[dt] = __builtin_amdgcn_mfma_f32_32x32x16_bf16(paf, vtf, oacc[dt], 0, 0, 0);
                        }
                    }
                }
                float rs = rs01 + rs23;
                rs += __shfl_xor(rs, 32, 64);
                lrun += rs;
            }
        }
    }

    // write partials (no normalization; proj gemm combines and divides)
    unsigned short* po = pO + ((size_t)ck * 4194304u);
    float* ls = lsum + ck * 65536;
#pragma unroll
    for (int r = 0; r < 16; ++r) {
        int ql = (r & 3) + 8 * (r >> 2) + 4 * hi;
        int q = q0 + w * 32 + ql;
        size_t ro = ((size_t)bh * 2048 + q) * 64;
        po[ro + l31]      = f2bf(oacc[0][r]);
        po[ro + 32 + l31] = f2bf(oacc[1][r]);
    }
    if (hi == 0) ls[bh * 2048 + q0 + w * 32 + l31] = lrun;
#undef LOADT
}

// ---------- launch ----------
extern "C" void kernel_launch(void* const* d_in, const int* in_sizes, int n_in,
                              void* d_out, int out_size, void* d_ws, size_t ws_size,
                              hipStream_t stream) {
    const float* x      = (const float*)d_in[0];   // [2,2048,1024]
    const float* v1     = (const float*)d_in[1];   // [2,2048,16,64]
    const float* w_q    = (const float*)d_in[2];
    const float* w_k    = (const float*)d_in[3];
    const float* w_v    = (const float*)d_in[4];
    const float* w_proj = (const float*)d_in[5];
    const float* lamb   = (const float*)d_in[6];
    float* out = (float*)d_out;

    char* ws = (char*)d_ws;
    unsigned short* xb      = (unsigned short*)(ws + 0);           // 8MB
    unsigned short* wall_b  = (unsigned short*)(ws + (8u  << 20)); // 8MB: [wq|wk|wv|wproj]
    unsigned short* wqkv_b  = wall_b;
    unsigned short* wproj_b = wall_b + 3u * 1048576u;
    unsigned short* qkvb    = (unsigned short*)(ws + (16u << 20)); // bf16 [4096][3072] = 24MB
    unsigned short* vtp     = (unsigned short*)(ws + (40u << 20)); // 8MB
    unsigned short* qbuf    = (unsigned short*)(ws + (48u << 20)); // 8MB
    unsigned short* kbuf    = (unsigned short*)(ws + (56u << 20)); // 8MB
    float*          cost    = (float*)        (ws + (72u << 20));
    float*          sint    = (float*)        (ws + (72u << 20) + 262144);
    unsigned short* pO      = (unsigned short*)(ws + (80u << 20)); // 2 x 8MB partials (stride 4194304 elems)
    float*          lsum    = (float*)        (ws + (112u << 20)); // 2 x 256KB

    prep_bf16<<<8448, 256, 0, stream>>>(x, w_q, w_k, w_v, w_proj, xb, wall_b, cost, sint);

    gemm_bf16<<<dim3(32, 24), 256, 0, stream>>>(xb, wqkv_b, qkvb, 3072, 1024);

    post_lerp<<<17408, 256, 0, stream>>>(qkvb, cost, sint, v1, lamb, qbuf, kbuf, vtp, out + 4194304);

    attn<<<1024, 256, 0, stream>>>(qbuf, kbuf, vtp, pO, lsum);

    gemm_proj<<<dim3(32, 8), 256, 0, stream>>>(pO, lsum, wproj_b, out);
}

// Round 15
// 130.534 us; speedup vs baseline: 1.0270x; 1.0270x over previous
//
#include <hip/hip_runtime.h>

// ---------- types ----------
typedef __bf16 bf16x8 __attribute__((ext_vector_type(8)));
typedef float f32x4 __attribute__((ext_vector_type(4)));
typedef float f32x16 __attribute__((ext_vector_type(16)));

__device__ __forceinline__ unsigned short f2bf(float f) {
    return __builtin_bit_cast(unsigned short, (__bf16)f);
}

__device__ __forceinline__ float bf2f(unsigned short u) {
    unsigned int x = ((unsigned int)u) << 16;
    return __builtin_bit_cast(float, x);
}

__device__ __forceinline__ unsigned int packbf2(float a, float b) {
    unsigned short lo = f2bf(a), hi = f2bf(b);
    return (unsigned int)lo | ((unsigned int)hi << 16);
}

__device__ __forceinline__ bf16x8 load_frag(const unsigned short* p) {
    int4 v = *reinterpret_cast<const int4*>(p);
    return __builtin_bit_cast(bf16x8, v);
}

__device__ __forceinline__ void gload_lds16(const unsigned short* g, unsigned short* l) {
    __builtin_amdgcn_global_load_lds((const __attribute__((address_space(1))) void*)g,
                                     (__attribute__((address_space(3))) void*)l, 16, 0, 0);
}

// ---------- prep: x + 4 weights -> bf16 (4 elems/thread); tail blocks build rope table ----------
__global__ __launch_bounds__(256) void prep_bf16(const float* __restrict__ x,
                                                 const float* __restrict__ wq,
                                                 const float* __restrict__ wk,
                                                 const float* __restrict__ wv,
                                                 const float* __restrict__ wp,
                                                 unsigned short* __restrict__ xb,
                                                 unsigned short* __restrict__ wall,
                                                 float* __restrict__ cost,
                                                 float* __restrict__ sint) {
    int bid = blockIdx.x;
    if (bid < 8192) {
        int i = (bid * 256 + threadIdx.x) * 4;            // 0..8M-4
        const float* src;
        unsigned short* dst;
        int soff, doff;
        if (i < (1 << 22)) {                               // x: 4M elems
            src = x; dst = xb; soff = i; doff = i;
        } else {
            int j = i - (1 << 22);                         // weights: 4x 1M elems
            int r = j >> 20;
            src = (r == 0) ? wq : ((r == 1) ? wk : ((r == 2) ? wv : wp));
            dst = wall; soff = j & 1048575; doff = j;
        }
        float4 v = *reinterpret_cast<const float4*>(&src[soff]);
        unsigned short tmp[4] = {f2bf(v.x), f2bf(v.y), f2bf(v.z), f2bf(v.w)};
        *reinterpret_cast<int2*>(&dst[doff]) = *reinterpret_cast<int2*>(tmp);
    } else {
        int i = (bid - 8192) * 256 + threadIdx.x;          // 2048*32
        int t = i >> 5, d = i & 31;
        float inv = powf(10000.0f, -(float)d / 32.0f);
        float f = (float)t * inv;
        cost[i] = cosf(f);
        sint[i] = sinf(f);
    }
}

// ---------- QKV GEMM with fused rmsnorm+rope (q,k) / lerp+v1-out (v) epilogue ----------
// Main loop identical to proven R9 gemm (gload_lds + both-sides XOR swizzle).
// Output tile holds 2 complete heads: d = j*16+cc, rope pair (d,d+32) = (j, j+2) register-local;
// RMS = per-lane sum over j + shfl_xor over the 16 cc lanes.
__global__ __launch_bounds__(256) void gemm_qkv(const unsigned short* __restrict__ A,
                                                const unsigned short* __restrict__ B,
                                                const float* __restrict__ cost,
                                                const float* __restrict__ sint,
                                                const float* __restrict__ v1,
                                                const float* __restrict__ lamb_p,
                                                unsigned short* __restrict__ qb,
                                                unsigned short* __restrict__ kb,
                                                unsigned short* __restrict__ vbv,
                                                float* __restrict__ outv1) {
    __shared__ __align__(16) unsigned short As[128 * 64];
    __shared__ __align__(16) unsigned short Bs[128 * 64];
    int tid = threadIdx.x;
    int lane = tid & 63;
    int w = tid >> 6;
    int wm = w >> 1, wn = w & 1;
    int m0 = blockIdx.x * 128;
    int n0 = blockIdx.y * 128;

    f32x4 acc[4][4] = {};

    int r8 = lane >> 3;              // 0..7
    int csrc = (lane & 7) ^ r8;      // pre-swizzled source 16B-unit (involution)

    for (int k0 = 0; k0 < 1024; k0 += 64) {
        __syncthreads();
#pragma unroll
        for (int c = 0; c < 4; ++c) {
            int row = 32 * w + 8 * c + r8;
            gload_lds16(&A[(size_t)(m0 + row) * 1024 + k0 + csrc * 8], &As[(32 * w + 8 * c) * 64]);
            gload_lds16(&B[(size_t)(n0 + row) * 1024 + k0 + csrc * 8], &Bs[(32 * w + 8 * c) * 64]);
        }
        __syncthreads();
#pragma unroll
        for (int kk = 0; kk < 2; ++kk) {
            int col16 = kk * 4 + (lane >> 4);
            bf16x8 af[4], bfr[4];
#pragma unroll
            for (int i = 0; i < 4; ++i) {
                int row = wm * 64 + i * 16 + (lane & 15);
                af[i] = load_frag(&As[row * 64 + (col16 ^ (row & 7)) * 8]);
            }
#pragma unroll
            for (int j = 0; j < 4; ++j) {
                int row = wn * 64 + j * 16 + (lane & 15);
                bfr[j] = load_frag(&Bs[row * 64 + (col16 ^ (row & 7)) * 8]);
            }
#pragma unroll
            for (int i = 0; i < 4; ++i)
#pragma unroll
                for (int j = 0; j < 4; ++j)
                    acc[i][j] = __builtin_amdgcn_mfma_f32_16x16x32_bf16(af[i], bfr[j], acc[i][j], 0, 0, 0);
        }
    }

    int r0 = (lane >> 4) * 4;
    int cc = lane & 15;
    int sec = blockIdx.y >> 3;               // 0=q, 1=k, 2=v
    int hh = (blockIdx.y & 7) * 2 + wn;      // head 0..15 for this wave column

    if (sec < 2) {
        unsigned short* dst = (sec == 0) ? qb : kb;
        float sc = (sec == 0) ? (0.125f * 1.44269504088896f) : 1.0f;  // fold softmax scale + log2e into q
#pragma unroll
        for (int i = 0; i < 4; ++i)
#pragma unroll
            for (int r = 0; r < 4; ++r) {
                float ss = 0.0f;
#pragma unroll
                for (int j = 0; j < 4; ++j) ss += acc[i][j][r] * acc[i][j][r];
                ss += __shfl_xor(ss, 1, 64);
                ss += __shfl_xor(ss, 2, 64);
                ss += __shfl_xor(ss, 4, 64);
                ss += __shfl_xor(ss, 8, 64);
                float rn = rsqrtf(ss * (1.0f / 64.0f) + 1e-6f);
                int mm = m0 + wm * 64 + i * 16 + r0 + r;
                int t = mm & 2047, b = mm >> 11;
                size_t rowb = ((size_t)((b * 16 + hh) * 2048 + t)) * 64;
#pragma unroll
                for (int j = 0; j < 2; ++j) {
                    int dm = j * 16 + cc;
                    float c = cost[t * 32 + dm], s_ = sint[t * 32 + dm];
                    float x1 = acc[i][j][r] * rn;
                    float x2 = acc[i][j + 2][r] * rn;
                    dst[rowb + dm]      = f2bf((x1 * c + x2 * s_) * sc);
                    dst[rowb + 32 + dm] = f2bf((x2 * c - x1 * s_) * sc);
                }
            }
    } else {
        float lam = lamb_p[0];
        float oml = 1.0f - lam;
#pragma unroll
        for (int i = 0; i < 4; ++i)
#pragma unroll
            for (int r = 0; r < 4; ++r) {
                int mm = m0 + wm * 64 + i * 16 + r0 + r;
                int t = mm & 2047, b = mm >> 11;
                size_t v1row = ((size_t)((b * 2048 + t) * 16 + hh)) * 64;
                size_t vbrow = ((size_t)((b * 16 + hh) * 2048 + t)) * 64;
#pragma unroll
                for (int j = 0; j < 4; ++j) {
                    int d = j * 16 + cc;
                    float v1v = v1[v1row + d];
                    outv1[v1row + d] = v1v;                 // v1 passthrough output
                    vbv[vbrow + d] = f2bf(oml * acc[i][j][r] + lam * v1v);
                }
            }
    }
}

// ---------- V transpose: vbv [bh][t][64] -> vt [bh][64][2048] (proven R1 body) ----------
__global__ __launch_bounds__(256) void transpose_v(const unsigned short* __restrict__ vbv,
                                                   unsigned short* __restrict__ vt) {
    __shared__ __align__(16) unsigned short tile[64][72];
    int bid = blockIdx.x;
    int bh = bid >> 5;
    int t0 = (bid & 31) * 64;
    int tid = threadIdx.x;
    int r = tid >> 3;            // 0..31
    int c = (tid & 7) * 8;       // 0..56
    const unsigned short* src = vbv + ((size_t)bh * 2048 + t0) * 64;
    *reinterpret_cast<int4*>(&tile[r][c]) =
        *reinterpret_cast<const int4*>(&src[(size_t)r * 64 + c]);
    *reinterpret_cast<int4*>(&tile[r + 32][c]) =
        *reinterpret_cast<const int4*>(&src[(size_t)(r + 32) * 64 + c]);
    __syncthreads();
    unsigned short* dst = vt + (size_t)bh * 64 * 2048 + t0;
    unsigned short tmp[8];
#pragma unroll
    for (int j = 0; j < 8; ++j) tmp[j] = tile[c + j][r];
    *reinterpret_cast<int4*>(&dst[(size_t)r * 2048 + c]) = *reinterpret_cast<int4*>(tmp);
#pragma unroll
    for (int j = 0; j < 8; ++j) tmp[j] = tile[c + j][r + 32];
    *reinterpret_cast<int4*>(&dst[(size_t)(r + 32) * 2048 + c]) = *reinterpret_cast<int4*>(tmp);
}

// ---------- proj GEMM with fused kv-split combine on the A side (proven R14) ----------
__global__ __launch_bounds__(256) void gemm_proj(const unsigned short* __restrict__ pO,
                                                 const float* __restrict__ lsum,
                                                 const unsigned short* __restrict__ B,
                                                 float* __restrict__ C) {
    __shared__ __align__(16) unsigned short As[128 * 64];
    __shared__ __align__(16) unsigned short Bs[128 * 64];
    int tid = threadIdx.x;
    int lane = tid & 63;
    int w = tid >> 6;
    int wm = w >> 1, wn = w & 1;
    int m0 = blockIdx.x * 128;
    int n0 = blockIdx.y * 128;

    f32x4 acc[4][4] = {};

    int r8 = lane >> 3;              // 0..7
    int c8 = lane & 7;               // LDS slot this thread fills
    int csrc = c8 ^ r8;              // global 16B-unit it loads (involution)

    for (int k0 = 0; k0 < 1024; k0 += 64) {
        int h = k0 >> 6;
        __syncthreads();
#pragma unroll
        for (int c = 0; c < 4; ++c) {
            int row = 32 * w + 8 * c + r8;
            int m = m0 + row;
            int bh = ((m >> 11) << 4) + h;
            int qi = m & 2047;
            int li = bh * 2048 + qi;
            size_t pi = (size_t)li * 64 + csrc * 8;
            int4 p0 = *reinterpret_cast<const int4*>(&pO[pi]);
            int4 p1 = *reinterpret_cast<const int4*>(&pO[4194304u + pi]);
            float linv = 1.0f / (lsum[li] + lsum[65536 + li]);
            const unsigned short* u0 = reinterpret_cast<const unsigned short*>(&p0);
            const unsigned short* u1 = reinterpret_cast<const unsigned short*>(&p1);
            unsigned short tmp[8];
#pragma unroll
            for (int j = 0; j < 8; ++j) tmp[j] = f2bf((bf2f(u0[j]) + bf2f(u1[j])) * linv);
            *reinterpret_cast<int4*>(&As[row * 64 + c8 * 8]) = *reinterpret_cast<int4*>(tmp);
            gload_lds16(&B[(size_t)(n0 + row) * 1024 + k0 + csrc * 8], &Bs[(32 * w + 8 * c) * 64]);
        }
        __syncthreads();
#pragma unroll
        for (int kk = 0; kk < 2; ++kk) {
            int col16 = kk * 4 + (lane >> 4);
            bf16x8 af[4], bfr[4];
#pragma unroll
            for (int i = 0; i < 4; ++i) {
                int row = wm * 64 + i * 16 + (lane & 15);
                af[i] = load_frag(&As[row * 64 + (col16 ^ (row & 7)) * 8]);
            }
#pragma unroll
            for (int j = 0; j < 4; ++j) {
                int row = wn * 64 + j * 16 + (lane & 15);
                bfr[j] = load_frag(&Bs[row * 64 + (col16 ^ (row & 7)) * 8]);
            }
#pragma unroll
            for (int i = 0; i < 4; ++i)
#pragma unroll
                for (int j = 0; j < 4; ++j)
                    acc[i][j] = __builtin_amdgcn_mfma_f32_16x16x32_bf16(af[i], bfr[j], acc[i][j], 0, 0, 0);
        }
    }
    int r0 = (lane >> 4) * 4;
    int cc = lane & 15;
#pragma unroll
    for (int i = 0; i < 4; ++i)
#pragma unroll
        for (int j = 0; j < 4; ++j)
#pragma unroll
            for (int r = 0; r < 4; ++r) {
                size_t m = m0 + wm * 64 + i * 16 + r0 + r;
                size_t n = n0 + wn * 64 + j * 16 + cc;
                C[m * 1024 + n] = acc[i][j][r];
            }
}

// ---------- flash attention, kv-split x2, causal, swapped-QK^T 32x32 MFMA (proven R13/R14) ----------
__global__ __launch_bounds__(256) void attn(const unsigned short* __restrict__ qb,
                                            const unsigned short* __restrict__ kb,
                                            const unsigned short* __restrict__ vt,   // [bh][64][2048]
                                            unsigned short* __restrict__ pO,         // [ck][bh][2048][64] bf16
                                            float* __restrict__ lsum) {              // [ck][bh][2048] f32
    __shared__ __align__(16) unsigned short Ks[64][72];   // [kv][d]
    __shared__ __align__(16) unsigned short Vt[64][72];   // [d][kv]
    int tid = threadIdx.x;
    int lane = tid & 63;
    int w = tid >> 6;
    int hi = lane >> 5;
    int l31 = lane & 31;

    int bid = blockIdx.x;                    // 0..1023
    int bh = bid & 31;
    int r5 = bid >> 5;                       // 0..31
    int qt = 15 - (r5 >> 1);                 // heavy first
    int ck = r5 & 1;
    int q0 = qt * 128;
    const size_t base = (size_t)bh * 2048 * 64;
    const unsigned short* vtb = vt + (size_t)bh * 64 * 2048;
    int ktlo = ck * (qt + 1);
    int kthi = (ck + 1) * (qt + 1);          // exclusive

    bf16x8 qf[4];
    int qrow = q0 + w * 32 + l31;
#pragma unroll
    for (int kd = 0; kd < 4; ++kd)
        qf[kd] = load_frag(&qb[base + (size_t)qrow * 64 + kd * 16 + hi * 8]);

    f32x16 oacc[2] = {};
    float lrun = 0.0f;

    int srow = tid >> 3;            // 0..31
    int scol = (tid & 7) * 8;       // 0..56
    int4 kr0, kr1, vr0, vr1;
#define LOADT(kt_)                                                                                    \
    do {                                                                                              \
        kr0 = *reinterpret_cast<const int4*>(&kb[base + (size_t)((kt_)*64 + srow) * 64 + scol]);      \
        kr1 = *reinterpret_cast<const int4*>(&kb[base + (size_t)((kt_)*64 + srow + 32) * 64 + scol]); \
        vr0 = *reinterpret_cast<const int4*>(&vtb[(size_t)srow * 2048 + (kt_)*64 + scol]);            \
        vr1 = *reinterpret_cast<const int4*>(&vtb[(size_t)(srow + 32) * 2048 + (kt_)*64 + scol]);     \
    } while (0)

    int qwlo = q0 + w * 32;
    {
        LOADT(ktlo);
        for (int kt = ktlo; kt < kthi; ++kt) {
            __syncthreads();
            *reinterpret_cast<int4*>(&Ks[srow][scol]) = kr0;
            *reinterpret_cast<int4*>(&Ks[srow + 32][scol]) = kr1;
            *reinterpret_cast<int4*>(&Vt[srow][scol]) = vr0;
            *reinterpret_cast<int4*>(&Vt[srow + 32][scol]) = vr1;
            __syncthreads();
            if (kt + 1 < kthi) LOADT(kt + 1);

            if (kt * 64 <= qwlo + 31) {
                bool diag = (kt * 64 + 63 > qwlo);
                float rs01 = 0.0f, rs23 = 0.0f;
#pragma unroll
                for (int ntl = 0; ntl < 2; ++ntl) {
                    f32x16 sacc = {};
#pragma unroll
                    for (int kd = 0; kd < 4; ++kd) {
                        bf16x8 kf = load_frag(&Ks[ntl * 32 + l31][kd * 16 + hi * 8]);
                        sacc = __builtin_amdgcn_mfma_f32_32x32x16_bf16(kf, qf[kd], sacc, 0, 0, 0);
                    }

#pragma unroll
                    for (int r = 0; r < 16; ++r) {
                        float s = sacc[r];
                        if (diag) {
                            int kvg = kt * 64 + ntl * 32 + (r & 3) + 8 * (r >> 2) + 4 * hi;
                            if (kvg > qrow) s = -3.0e38f;
                        }
                        float e = __builtin_amdgcn_exp2f(s);
                        sacc[r] = e;
                        if (r & 2) rs23 += e; else rs01 += e;
                    }

                    unsigned int wAa[4], wBb[4];
#pragma unroll
                    for (int rr = 0; rr < 4; ++rr) {
                        wAa[rr] = packbf2(sacc[4 * rr + 0], sacc[4 * rr + 1]);
                        wBb[rr] = packbf2(sacc[4 * rr + 2], sacc[4 * rr + 3]);
                    }

#pragma unroll
                    for (int ks2 = 0; ks2 < 2; ++ks2) {
                        int b2 = ks2 * 2;
                        auto rA = __builtin_amdgcn_permlane32_swap(wAa[b2], wAa[b2 + 1], false, false);
                        auto rB = __builtin_amdgcn_permlane32_swap(wBb[b2], wBb[b2 + 1], false, false);
                        uint4 pa;
                        pa.x = rA[0];   // kv 16ks+8hi+{0,1}
                        pa.y = rB[0];   // +{2,3}
                        pa.z = rA[1];   // +{4,5}
                        pa.w = rB[1];   // +{6,7}
                        bf16x8 paf = __builtin_bit_cast(bf16x8, pa);
                        int ks = ntl * 2 + ks2;
#pragma unroll
                        for (int dt = 0; dt < 2; ++dt) {
                            bf16x8 vtf = load_frag(&Vt[dt * 32 + l31][ks * 16 + hi * 8]);
                            oacc[dt] = __builtin_amdgcn_mfma_f32_32x32x16_bf16(paf, vtf, oacc[dt], 0, 0, 0);
                        }
                    }
                }
                float rs = rs01 + rs23;
                rs += __shfl_xor(rs, 32, 64);
                lrun += rs;
            }
        }
    }

    unsigned short* po = pO + ((size_t)ck * 4194304u);
    float* ls = lsum + ck * 65536;
#pragma unroll
    for (int r = 0; r < 16; ++r) {
        int ql = (r & 3) + 8 * (r >> 2) + 4 * hi;
        int q = q0 + w * 32 + ql;
        size_t ro = ((size_t)bh * 2048 + q) * 64;
        po[ro + l31]      = f2bf(oacc[0][r]);
        po[ro + 32 + l31] = f2bf(oacc[1][r]);
    }
    if (hi == 0) ls[bh * 2048 + q0 + w * 32 + l31] = lrun;
#undef LOADT
}

// ---------- launch ----------
extern "C" void kernel_launch(void* const* d_in, const int* in_sizes, int n_in,
                              void* d_out, int out_size, void* d_ws, size_t ws_size,
                              hipStream_t stream) {
    const float* x      = (const float*)d_in[0];   // [2,2048,1024]
    const float* v1     = (const float*)d_in[1];   // [2,2048,16,64]
    const float* w_q    = (const float*)d_in[2];
    const float* w_k    = (const float*)d_in[3];
    const float* w_v    = (const float*)d_in[4];
    const float* w_proj = (const float*)d_in[5];
    const float* lamb   = (const float*)d_in[6];
    float* out = (float*)d_out;

    char* ws = (char*)d_ws;
    unsigned short* xb      = (unsigned short*)(ws + 0);           // 8MB
    unsigned short* wall_b  = (unsigned short*)(ws + (8u  << 20)); // 8MB: [wq|wk|wv|wproj]
    unsigned short* wqkv_b  = wall_b;
    unsigned short* wproj_b = wall_b + 3u * 1048576u;
    unsigned short* vbuf    = (unsigned short*)(ws + (16u << 20)); // 8MB [bh][t][64]
    unsigned short* vtp     = (unsigned short*)(ws + (40u << 20)); // 8MB [bh][64][2048]
    unsigned short* qbuf    = (unsigned short*)(ws + (48u << 20)); // 8MB
    unsigned short* kbuf    = (unsigned short*)(ws + (56u << 20)); // 8MB
    float*          cost    = (float*)        (ws + (72u << 20));
    float*          sint    = (float*)        (ws + (72u << 20) + 262144);
    unsigned short* pO      = (unsigned short*)(ws + (80u << 20)); // 2 x 8MB partials (stride 4194304 elems)
    float*          lsum    = (float*)        (ws + (112u << 20)); // 2 x 256KB

    prep_bf16<<<8448, 256, 0, stream>>>(x, w_q, w_k, w_v, w_proj, xb, wall_b, cost, sint);

    gemm_qkv<<<dim3(32, 24), 256, 0, stream>>>(xb, wqkv_b, cost, sint, v1, lamb,
                                               qbuf, kbuf, vbuf, out + 4194304);

    transpose_v<<<1024, 256, 0, stream>>>(vbuf, vtp);

    attn<<<1024, 256, 0, stream>>>(qbuf, kbuf, vtp, pO, lsum);

    gemm_proj<<<dim3(32, 8), 256, 0, stream>>>(pO, lsum, wproj_b, out);
}

// Round 16
// 129.852 us; speedup vs baseline: 1.0324x; 1.0053x over previous
//
#include <hip/hip_runtime.h>

// ---------- types ----------
typedef __bf16 bf16x8 __attribute__((ext_vector_type(8)));
typedef float f32x4 __attribute__((ext_vector_type(4)));
typedef float f32x16 __attribute__((ext_vector_type(16)));

__device__ __forceinline__ unsigned short f2bf(float f) {
    return __builtin_bit_cast(unsigned short, (__bf16)f);
}

__device__ __forceinline__ float bf2f(unsigned short u) {
    unsigned int x = ((unsigned int)u) << 16;
    return __builtin_bit_cast(float, x);
}

__device__ __forceinline__ unsigned int packbf2(float a, float b) {
    unsigned short lo = f2bf(a), hi = f2bf(b);
    return (unsigned int)lo | ((unsigned int)hi << 16);
}

__device__ __forceinline__ bf16x8 load_frag(const unsigned short* p) {
    int4 v = *reinterpret_cast<const int4*>(p);
    return __builtin_bit_cast(bf16x8, v);
}

__device__ __forceinline__ void gload_lds16(const unsigned short* g, unsigned short* l) {
    __builtin_amdgcn_global_load_lds((const __attribute__((address_space(1))) void*)g,
                                     (__attribute__((address_space(3))) void*)l, 16, 0, 0);
}

// ---------- prep: x + 4 weights -> bf16 (4 elems/thread); tail blocks build rope table ----------
__global__ __launch_bounds__(256) void prep_bf16(const float* __restrict__ x,
                                                 const float* __restrict__ wq,
                                                 const float* __restrict__ wk,
                                                 const float* __restrict__ wv,
                                                 const float* __restrict__ wp,
                                                 unsigned short* __restrict__ xb,
                                                 unsigned short* __restrict__ wall,
                                                 float* __restrict__ cost,
                                                 float* __restrict__ sint) {
    int bid = blockIdx.x;
    if (bid < 8192) {
        int i = (bid * 256 + threadIdx.x) * 4;            // 0..8M-4
        const float* src;
        unsigned short* dst;
        int soff, doff;
        if (i < (1 << 22)) {                               // x: 4M elems
            src = x; dst = xb; soff = i; doff = i;
        } else {
            int j = i - (1 << 22);                         // weights: 4x 1M elems
            int r = j >> 20;
            src = (r == 0) ? wq : ((r == 1) ? wk : ((r == 2) ? wv : wp));
            dst = wall; soff = j & 1048575; doff = j;
        }
        float4 v = *reinterpret_cast<const float4*>(&src[soff]);
        unsigned short tmp[4] = {f2bf(v.x), f2bf(v.y), f2bf(v.z), f2bf(v.w)};
        *reinterpret_cast<int2*>(&dst[doff]) = *reinterpret_cast<int2*>(tmp);
    } else {
        int i = (bid - 8192) * 256 + threadIdx.x;          // 2048*32
        int t = i >> 5, d = i & 31;
        float inv = powf(10000.0f, -(float)d / 32.0f);
        float f = (float)t * inv;
        cost[i] = cosf(f);
        sint[i] = sinf(f);
    }
}

// ---------- Q/K GEMM with fused rmsnorm+rope epilogue (grid 32 x 16) ----------
// Main loop = proven R9 gemm (gload_lds + both-sides XOR swizzle). blockIdx.y<8 -> q, else k.
__global__ __launch_bounds__(256) void gemm_qk(const unsigned short* __restrict__ A,
                                               const unsigned short* __restrict__ B,
                                               const float* __restrict__ cost,
                                               const float* __restrict__ sint,
                                               unsigned short* __restrict__ qb,
                                               unsigned short* __restrict__ kb) {
    __shared__ __align__(16) unsigned short As[128 * 64];
    __shared__ __align__(16) unsigned short Bs[128 * 64];
    int tid = threadIdx.x;
    int lane = tid & 63;
    int w = tid >> 6;
    int wm = w >> 1, wn = w & 1;
    int m0 = blockIdx.x * 128;
    int n0 = blockIdx.y * 128;

    f32x4 acc[4][4] = {};

    int r8 = lane >> 3;
    int csrc = (lane & 7) ^ r8;      // pre-swizzled source 16B-unit (involution)

    for (int k0 = 0; k0 < 1024; k0 += 64) {
        __syncthreads();
#pragma unroll
        for (int c = 0; c < 4; ++c) {
            int row = 32 * w + 8 * c + r8;
            gload_lds16(&A[(size_t)(m0 + row) * 1024 + k0 + csrc * 8], &As[(32 * w + 8 * c) * 64]);
            gload_lds16(&B[(size_t)(n0 + row) * 1024 + k0 + csrc * 8], &Bs[(32 * w + 8 * c) * 64]);
        }
        __syncthreads();
#pragma unroll
        for (int kk = 0; kk < 2; ++kk) {
            int col16 = kk * 4 + (lane >> 4);
            bf16x8 af[4], bfr[4];
#pragma unroll
            for (int i = 0; i < 4; ++i) {
                int row = wm * 64 + i * 16 + (lane & 15);
                af[i] = load_frag(&As[row * 64 + (col16 ^ (row & 7)) * 8]);
            }
#pragma unroll
            for (int j = 0; j < 4; ++j) {
                int row = wn * 64 + j * 16 + (lane & 15);
                bfr[j] = load_frag(&Bs[row * 64 + (col16 ^ (row & 7)) * 8]);
            }
#pragma unroll
            for (int i = 0; i < 4; ++i)
#pragma unroll
                for (int j = 0; j < 4; ++j)
                    acc[i][j] = __builtin_amdgcn_mfma_f32_16x16x32_bf16(af[i], bfr[j], acc[i][j], 0, 0, 0);
        }
    }

    int r0 = (lane >> 4) * 4;
    int cc = lane & 15;
    int sec = blockIdx.y >> 3;               // 0=q, 1=k
    int hh = (blockIdx.y & 7) * 2 + wn;      // head 0..15
    unsigned short* dst = (sec == 0) ? qb : kb;
    float sc = (sec == 0) ? (0.125f * 1.44269504088896f) : 1.0f;  // fold softmax scale + log2e into q
#pragma unroll
    for (int i = 0; i < 4; ++i)
#pragma unroll
        for (int r = 0; r < 4; ++r) {
            float ss = 0.0f;
#pragma unroll
            for (int j = 0; j < 4; ++j) ss += acc[i][j][r] * acc[i][j][r];
            ss += __shfl_xor(ss, 1, 64);
            ss += __shfl_xor(ss, 2, 64);
            ss += __shfl_xor(ss, 4, 64);
            ss += __shfl_xor(ss, 8, 64);
            float rn = rsqrtf(ss * (1.0f / 64.0f) + 1e-6f);
            int mm = m0 + wm * 64 + i * 16 + r0 + r;
            int t = mm & 2047, b = mm >> 11;
            size_t rowb = ((size_t)((b * 16 + hh) * 2048 + t)) * 64;
#pragma unroll
            for (int j = 0; j < 2; ++j) {
                int dm = j * 16 + cc;
                float c = cost[t * 32 + dm], s_ = sint[t * 32 + dm];
                float x1 = acc[i][j][r] * rn;
                float x2 = acc[i][j + 2][r] * rn;
                dst[rowb + dm]      = f2bf((x1 * c + x2 * s_) * sc);
                dst[rowb + 32 + dm] = f2bf((x2 * c - x1 * s_) * sc);
            }
        }
}

// ---------- V GEMM with fused lerp + v1-passthrough + in-LDS transpose (grid 32 x 8) ----------
// Writes vt [bh][64][2048] directly; outv1 = v1 (f32). LDS tile aliases dead As/Bs after K-loop.
__global__ __launch_bounds__(256) void gemm_v(const unsigned short* __restrict__ A,
                                              const unsigned short* __restrict__ Bv,  // wv rows
                                              const float* __restrict__ v1,
                                              const float* __restrict__ lamb_p,
                                              unsigned short* __restrict__ vt,
                                              float* __restrict__ outv1) {
    __shared__ __align__(16) unsigned short smem[2 * 128 * 72];   // 36864B; As/Bs alias front 32KB
    unsigned short* As = smem;
    unsigned short* Bs = smem + 128 * 64;
    int tid = threadIdx.x;
    int lane = tid & 63;
    int w = tid >> 6;
    int wm = w >> 1, wn = w & 1;
    int m0 = blockIdx.x * 128;
    int n0 = blockIdx.y * 128;

    f32x4 acc[4][4] = {};

    int r8 = lane >> 3;
    int csrc = (lane & 7) ^ r8;

    for (int k0 = 0; k0 < 1024; k0 += 64) {
        __syncthreads();
#pragma unroll
        for (int c = 0; c < 4; ++c) {
            int row = 32 * w + 8 * c + r8;
            gload_lds16(&A[(size_t)(m0 + row) * 1024 + k0 + csrc * 8], &As[(32 * w + 8 * c) * 64]);
            gload_lds16(&Bv[(size_t)(n0 + row) * 1024 + k0 + csrc * 8], &Bs[(32 * w + 8 * c) * 64]);
        }
        __syncthreads();
#pragma unroll
        for (int kk = 0; kk < 2; ++kk) {
            int col16 = kk * 4 + (lane >> 4);
            bf16x8 af[4], bfr[4];
#pragma unroll
            for (int i = 0; i < 4; ++i) {
                int row = wm * 64 + i * 16 + (lane & 15);
                af[i] = load_frag(&As[row * 64 + (col16 ^ (row & 7)) * 8]);
            }
#pragma unroll
            for (int j = 0; j < 4; ++j) {
                int row = wn * 64 + j * 16 + (lane & 15);
                bfr[j] = load_frag(&Bs[row * 64 + (col16 ^ (row & 7)) * 8]);
            }
#pragma unroll
            for (int i = 0; i < 4; ++i)
#pragma unroll
                for (int j = 0; j < 4; ++j)
                    acc[i][j] = __builtin_amdgcn_mfma_f32_16x16x32_bf16(af[i], bfr[j], acc[i][j], 0, 0, 0);
        }
    }

    // lerp + v1 passthrough, write into per-head LDS tile [head][t_local 128][d 64 +pad 72]
    typedef unsigned short (*tile_t)[128][72];
    tile_t tile = reinterpret_cast<tile_t>(smem);
    int r0 = (lane >> 4) * 4;
    int cc = lane & 15;
    int hh = blockIdx.y * 2 + wn;            // head 0..15
    float lam = lamb_p[0];
    float oml = 1.0f - lam;
    __syncthreads();                         // As/Bs dead; safe to overlay
#pragma unroll
    for (int i = 0; i < 4; ++i)
#pragma unroll
        for (int r = 0; r < 4; ++r) {
            int tl = wm * 64 + i * 16 + r0 + r;      // 0..127
            int mm = m0 + tl;
            int t = mm & 2047, b = mm >> 11;
            size_t v1row = ((size_t)((b * 2048 + t) * 16 + hh)) * 64;
#pragma unroll
            for (int j = 0; j < 4; ++j) {
                int d = j * 16 + cc;
                float v1v = v1[v1row + d];
                outv1[v1row + d] = v1v;              // v1 passthrough output
                tile[wn][tl][d] = f2bf(oml * acc[i][j][r] + lam * v1v);
            }
        }
    __syncthreads();

    // transposed store: vt[bh][d][t0+..]
    int h2 = tid >> 7;                       // 0/1
    int idx = tid & 127;
    int rr2 = idx >> 2;                      // 0..31 -> d rows rr2, rr2+32
    int c2 = (idx & 3) * 8;                  // 0,8,16,24
    int hhs = blockIdx.y * 2 + h2;
    int t0 = m0 & 2047;
    int bb = m0 >> 11;
    unsigned short* dst = vt + ((size_t)(bb * 16 + hhs)) * 64 * 2048;
    unsigned short tmp[8];
#pragma unroll
    for (int tb = 0; tb < 128; tb += 32) {
#pragma unroll
        for (int j = 0; j < 8; ++j) tmp[j] = tile[h2][tb + c2 + j][rr2];
        *reinterpret_cast<int4*>(&dst[(size_t)rr2 * 2048 + t0 + tb + c2]) = *reinterpret_cast<int4*>(tmp);
#pragma unroll
        for (int j = 0; j < 8; ++j) tmp[j] = tile[h2][tb + c2 + j][rr2 + 32];
        *reinterpret_cast<int4*>(&dst[(size_t)(rr2 + 32) * 2048 + t0 + tb + c2]) = *reinterpret_cast<int4*>(tmp);
    }
}

// ---------- proj GEMM with fused kv-split combine on the A side (proven R14) ----------
__global__ __launch_bounds__(256) void gemm_proj(const unsigned short* __restrict__ pO,
                                                 const float* __restrict__ lsum,
                                                 const unsigned short* __restrict__ B,
                                                 float* __restrict__ C) {
    __shared__ __align__(16) unsigned short As[128 * 64];
    __shared__ __align__(16) unsigned short Bs[128 * 64];
    int tid = threadIdx.x;
    int lane = tid & 63;
    int w = tid >> 6;
    int wm = w >> 1, wn = w & 1;
    int m0 = blockIdx.x * 128;
    int n0 = blockIdx.y * 128;

    f32x4 acc[4][4] = {};

    int r8 = lane >> 3;
    int c8 = lane & 7;
    int csrc = c8 ^ r8;

    for (int k0 = 0; k0 < 1024; k0 += 64) {
        int h = k0 >> 6;
        __syncthreads();
#pragma unroll
        for (int c = 0; c < 4; ++c) {
            int row = 32 * w + 8 * c + r8;
            int m = m0 + row;
            int bh = ((m >> 11) << 4) + h;
            int qi = m & 2047;
            int li = bh * 2048 + qi;
            size_t pi = (size_t)li * 64 + csrc * 8;
            int4 p0 = *reinterpret_cast<const int4*>(&pO[pi]);
            int4 p1 = *reinterpret_cast<const int4*>(&pO[4194304u + pi]);
            float linv = 1.0f / (lsum[li] + lsum[65536 + li]);
            const unsigned short* u0 = reinterpret_cast<const unsigned short*>(&p0);
            const unsigned short* u1 = reinterpret_cast<const unsigned short*>(&p1);
            unsigned short tmp[8];
#pragma unroll
            for (int j = 0; j < 8; ++j) tmp[j] = f2bf((bf2f(u0[j]) + bf2f(u1[j])) * linv);
            *reinterpret_cast<int4*>(&As[row * 64 + c8 * 8]) = *reinterpret_cast<int4*>(tmp);
            gload_lds16(&B[(size_t)(n0 + row) * 1024 + k0 + csrc * 8], &Bs[(32 * w + 8 * c) * 64]);
        }
        __syncthreads();
#pragma unroll
        for (int kk = 0; kk < 2; ++kk) {
            int col16 = kk * 4 + (lane >> 4);
            bf16x8 af[4], bfr[4];
#pragma unroll
            for (int i = 0; i < 4; ++i) {
                int row = wm * 64 + i * 16 + (lane & 15);
                af[i] = load_frag(&As[row * 64 + (col16 ^ (row & 7)) * 8]);
            }
#pragma unroll
            for (int j = 0; j < 4; ++j) {
                int row = wn * 64 + j * 16 + (lane & 15);
                bfr[j] = load_frag(&Bs[row * 64 + (col16 ^ (row & 7)) * 8]);
            }
#pragma unroll
            for (int i = 0; i < 4; ++i)
#pragma unroll
                for (int j = 0; j < 4; ++j)
                    acc[i][j] = __builtin_amdgcn_mfma_f32_16x16x32_bf16(af[i], bfr[j], acc[i][j], 0, 0, 0);
        }
    }
    int r0 = (lane >> 4) * 4;
    int cc = lane & 15;
#pragma unroll
    for (int i = 0; i < 4; ++i)
#pragma unroll
        for (int j = 0; j < 4; ++j)
#pragma unroll
            for (int r = 0; r < 4; ++r) {
                size_t m = m0 + wm * 64 + i * 16 + r0 + r;
                size_t n = n0 + wn * 64 + j * 16 + cc;
                C[m * 1024 + n] = acc[i][j][r];
            }
}

// ---------- flash attention, kv-split x2, causal, swapped-QK^T 32x32 MFMA (proven R13/R14) ----------
__global__ __launch_bounds__(256) void attn(const unsigned short* __restrict__ qb,
                                            const unsigned short* __restrict__ kb,
                                            const unsigned short* __restrict__ vt,   // [bh][64][2048]
                                            unsigned short* __restrict__ pO,         // [ck][bh][2048][64] bf16
                                            float* __restrict__ lsum) {              // [ck][bh][2048] f32
    __shared__ __align__(16) unsigned short Ks[64][72];   // [kv][d]
    __shared__ __align__(16) unsigned short Vt[64][72];   // [d][kv]
    int tid = threadIdx.x;
    int lane = tid & 63;
    int w = tid >> 6;
    int hi = lane >> 5;
    int l31 = lane & 31;

    int bid = blockIdx.x;                    // 0..1023
    int bh = bid & 31;
    int r5 = bid >> 5;                       // 0..31
    int qt = 15 - (r5 >> 1);                 // heavy first
    int ck = r5 & 1;
    int q0 = qt * 128;
    const size_t base = (size_t)bh * 2048 * 64;
    const unsigned short* vtb = vt + (size_t)bh * 64 * 2048;
    int ktlo = ck * (qt + 1);
    int kthi = (ck + 1) * (qt + 1);          // exclusive

    bf16x8 qf[4];
    int qrow = q0 + w * 32 + l31;
#pragma unroll
    for (int kd = 0; kd < 4; ++kd)
        qf[kd] = load_frag(&qb[base + (size_t)qrow * 64 + kd * 16 + hi * 8]);

    f32x16 oacc[2] = {};
    float lrun = 0.0f;

    int srow = tid >> 3;            // 0..31
    int scol = (tid & 7) * 8;       // 0..56
    int4 kr0, kr1, vr0, vr1;
#define LOADT(kt_)                                                                                    \
    do {                                                                                              \
        kr0 = *reinterpret_cast<const int4*>(&kb[base + (size_t)((kt_)*64 + srow) * 64 + scol]);      \
        kr1 = *reinterpret_cast<const int4*>(&kb[base + (size_t)((kt_)*64 + srow + 32) * 64 + scol]); \
        vr0 = *reinterpret_cast<const int4*>(&vtb[(size_t)srow * 2048 + (kt_)*64 + scol]);            \
        vr1 = *reinterpret_cast<const int4*>(&vtb[(size_t)(srow + 32) * 2048 + (kt_)*64 + scol]);     \
    } while (0)

    int qwlo = q0 + w * 32;
    {
        LOADT(ktlo);
        for (int kt = ktlo; kt < kthi; ++kt) {
            __syncthreads();
            *reinterpret_cast<int4*>(&Ks[srow][scol]) = kr0;
            *reinterpret_cast<int4*>(&Ks[srow + 32][scol]) = kr1;
            *reinterpret_cast<int4*>(&Vt[srow][scol]) = vr0;
            *reinterpret_cast<int4*>(&Vt[srow + 32][scol]) = vr1;
            __syncthreads();
            if (kt + 1 < kthi) LOADT(kt + 1);

            if (kt * 64 <= qwlo + 31) {
                bool diag = (kt * 64 + 63 > qwlo);
                float rs01 = 0.0f, rs23 = 0.0f;
#pragma unroll
                for (int ntl = 0; ntl < 2; ++ntl) {
                    f32x16 sacc = {};
#pragma unroll
                    for (int kd = 0; kd < 4; ++kd) {
                        bf16x8 kf = load_frag(&Ks[ntl * 32 + l31][kd * 16 + hi * 8]);
                        sacc = __builtin_amdgcn_mfma_f32_32x32x16_bf16(kf, qf[kd], sacc, 0, 0, 0);
                    }

#pragma unroll
                    for (int r = 0; r < 16; ++r) {
                        float s = sacc[r];
                        if (diag) {
                            int kvg = kt * 64 + ntl * 32 + (r & 3) + 8 * (r >> 2) + 4 * hi;
                            if (kvg > qrow) s = -3.0e38f;
                        }
                        float e = __builtin_amdgcn_exp2f(s);
                        sacc[r] = e;
                        if (r & 2) rs23 += e; else rs01 += e;
                    }

                    unsigned int wAa[4], wBb[4];
#pragma unroll
                    for (int rr = 0; rr < 4; ++rr) {
                        wAa[rr] = packbf2(sacc[4 * rr + 0], sacc[4 * rr + 1]);
                        wBb[rr] = packbf2(sacc[4 * rr + 2], sacc[4 * rr + 3]);
                    }

#pragma unroll
                    for (int ks2 = 0; ks2 < 2; ++ks2) {
                        int b2 = ks2 * 2;
                        auto rA = __builtin_amdgcn_permlane32_swap(wAa[b2], wAa[b2 + 1], false, false);
                        auto rB = __builtin_amdgcn_permlane32_swap(wBb[b2], wBb[b2 + 1], false, false);
                        uint4 pa;
                        pa.x = rA[0];   // kv 16ks+8hi+{0,1}
                        pa.y = rB[0];   // +{2,3}
                        pa.z = rA[1];   // +{4,5}
                        pa.w = rB[1];   // +{6,7}
                        bf16x8 paf = __builtin_bit_cast(bf16x8, pa);
                        int ks = ntl * 2 + ks2;
#pragma unroll
                        for (int dt = 0; dt < 2; ++dt) {
                            bf16x8 vtf = load_frag(&Vt[dt * 32 + l31][ks * 16 + hi * 8]);
                            oacc[dt] = __builtin_amdgcn_mfma_f32_32x32x16_bf16(paf, vtf, oacc[dt], 0, 0, 0);
                        }
                    }
                }
                float rs = rs01 + rs23;
                rs += __shfl_xor(rs, 32, 64);
                lrun += rs;
            }
        }
    }

    unsigned short* po = pO + ((size_t)ck * 4194304u);
    float* ls = lsum + ck * 65536;
#pragma unroll
    for (int r = 0; r < 16; ++r) {
        int ql = (r & 3) + 8 * (r >> 2) + 4 * hi;
        int q = q0 + w * 32 + ql;
        size_t ro = ((size_t)bh * 2048 + q) * 64;
        po[ro + l31]      = f2bf(oacc[0][r]);
        po[ro + 32 + l31] = f2bf(oacc[1][r]);
    }
    if (hi == 0) ls[bh * 2048 + q0 + w * 32 + l31] = lrun;
#undef LOADT
}

// ---------- launch ----------
extern "C" void kernel_launch(void* const* d_in, const int* in_sizes, int n_in,
                              void* d_out, int out_size, void* d_ws, size_t ws_size,
                              hipStream_t stream) {
    const float* x      = (const float*)d_in[0];   // [2,2048,1024]
    const float* v1     = (const float*)d_in[1];   // [2,2048,16,64]
    const float* w_q    = (const float*)d_in[2];
    const float* w_k    = (const float*)d_in[3];
    const float* w_v    = (const float*)d_in[4];
    const float* w_proj = (const float*)d_in[5];
    const float* lamb   = (const float*)d_in[6];
    float* out = (float*)d_out;

    char* ws = (char*)d_ws;
    unsigned short* xb      = (unsigned short*)(ws + 0);           // 8MB
    unsigned short* wall_b  = (unsigned short*)(ws + (8u  << 20)); // 8MB: [wq|wk|wv|wproj]
    unsigned short* wqkv_b  = wall_b;
    unsigned short* wv_b    = wall_b + 2u * 1048576u;
    unsigned short* wproj_b = wall_b + 3u * 1048576u;
    unsigned short* vtp     = (unsigned short*)(ws + (40u << 20)); // 8MB [bh][64][2048]
    unsigned short* qbuf    = (unsigned short*)(ws + (48u << 20)); // 8MB
    unsigned short* kbuf    = (unsigned short*)(ws + (56u << 20)); // 8MB
    float*          cost    = (float*)        (ws + (72u << 20));
    float*          sint    = (float*)        (ws + (72u << 20) + 262144);
    unsigned short* pO      = (unsigned short*)(ws + (80u << 20)); // 2 x 8MB partials (stride 4194304 elems)
    float*          lsum    = (float*)        (ws + (112u << 20)); // 2 x 256KB

    prep_bf16<<<8448, 256, 0, stream>>>(x, w_q, w_k, w_v, w_proj, xb, wall_b, cost, sint);

    gemm_qk<<<dim3(32, 16), 256, 0, stream>>>(xb, wqkv_b, cost, sint, qbuf, kbuf);
    gemm_v<<<dim3(32, 8), 256, 0, stream>>>(xb, wv_b, v1, lamb, vtp, out + 4194304);

    attn<<<1024, 256, 0, stream>>>(qbuf, kbuf, vtp, pO, lsum);

    gemm_proj<<<dim3(32, 8), 256, 0, stream>>>(pO, lsum, wproj_b, out);
}

// Round 17
// 129.440 us; speedup vs baseline: 1.0357x; 1.0032x over previous
//
#include <hip/hip_runtime.h>

// ---------- types ----------
typedef __bf16 bf16x8 __attribute__((ext_vector_type(8)));
typedef float f32x4 __attribute__((ext_vector_type(4)));
typedef float f32x16 __attribute__((ext_vector_type(16)));

__device__ __forceinline__ unsigned short f2bf(float f) {
    return __builtin_bit_cast(unsigned short, (__bf16)f);
}

__device__ __forceinline__ float bf2f(unsigned short u) {
    unsigned int x = ((unsigned int)u) << 16;
    return __builtin_bit_cast(float, x);
}

__device__ __forceinline__ unsigned int packbf2(float a, float b) {
    unsigned short lo = f2bf(a), hi = f2bf(b);
    return (unsigned int)lo | ((unsigned int)hi << 16);
}

__device__ __forceinline__ bf16x8 load_frag(const unsigned short* p) {
    int4 v = *reinterpret_cast<const int4*>(p);
    return __builtin_bit_cast(bf16x8, v);
}

__device__ __forceinline__ void gload_lds16(const unsigned short* g, unsigned short* l) {
    __builtin_amdgcn_global_load_lds((const __attribute__((address_space(1))) void*)g,
                                     (__attribute__((address_space(3))) void*)l, 16, 0, 0);
}

// ---------- prep: x + 4 weights -> bf16 (4 elems/thread); tail blocks build rope table ----------
__global__ __launch_bounds__(256) void prep_bf16(const float* __restrict__ x,
                                                 const float* __restrict__ wq,
                                                 const float* __restrict__ wk,
                                                 const float* __restrict__ wv,
                                                 const float* __restrict__ wp,
                                                 unsigned short* __restrict__ xb,
                                                 unsigned short* __restrict__ wall,
                                                 float* __restrict__ cost,
                                                 float* __restrict__ sint) {
    int bid = blockIdx.x;
    if (bid < 8192) {
        int i = (bid * 256 + threadIdx.x) * 4;            // 0..8M-4
        const float* src;
        unsigned short* dst;
        int soff, doff;
        if (i < (1 << 22)) {                               // x: 4M elems
            src = x; dst = xb; soff = i; doff = i;
        } else {
            int j = i - (1 << 22);                         // weights: 4x 1M elems
            int r = j >> 20;
            src = (r == 0) ? wq : ((r == 1) ? wk : ((r == 2) ? wv : wp));
            dst = wall; soff = j & 1048575; doff = j;
        }
        float4 v = *reinterpret_cast<const float4*>(&src[soff]);
        unsigned short tmp[4] = {f2bf(v.x), f2bf(v.y), f2bf(v.z), f2bf(v.w)};
        *reinterpret_cast<int2*>(&dst[doff]) = *reinterpret_cast<int2*>(tmp);
    } else {
        int i = (bid - 8192) * 256 + threadIdx.x;          // 2048*32
        int t = i >> 5, d = i & 31;
        float inv = powf(10000.0f, -(float)d / 32.0f);
        float f = (float)t * inv;
        cost[i] = cosf(f);
        sint[i] = sinf(f);
    }
}

// ---------- Q/K GEMM with fused rmsnorm+rope epilogue (grid 32 x 16) ----------
__global__ __launch_bounds__(256) void gemm_qk(const unsigned short* __restrict__ A,
                                               const unsigned short* __restrict__ B,
                                               const float* __restrict__ cost,
                                               const float* __restrict__ sint,
                                               unsigned short* __restrict__ qb,
                                               unsigned short* __restrict__ kb) {
    __shared__ __align__(16) unsigned short As[128 * 64];
    __shared__ __align__(16) unsigned short Bs[128 * 64];
    int tid = threadIdx.x;
    int lane = tid & 63;
    int w = tid >> 6;
    int wm = w >> 1, wn = w & 1;
    int m0 = blockIdx.x * 128;
    int n0 = blockIdx.y * 128;

    f32x4 acc[4][4] = {};

    int r8 = lane >> 3;
    int csrc = (lane & 7) ^ r8;      // pre-swizzled source 16B-unit (involution)

    for (int k0 = 0; k0 < 1024; k0 += 64) {
        __syncthreads();
#pragma unroll
        for (int c = 0; c < 4; ++c) {
            int row = 32 * w + 8 * c + r8;
            gload_lds16(&A[(size_t)(m0 + row) * 1024 + k0 + csrc * 8], &As[(32 * w + 8 * c) * 64]);
            gload_lds16(&B[(size_t)(n0 + row) * 1024 + k0 + csrc * 8], &Bs[(32 * w + 8 * c) * 64]);
        }
        __syncthreads();
#pragma unroll
        for (int kk = 0; kk < 2; ++kk) {
            int col16 = kk * 4 + (lane >> 4);
            bf16x8 af[4], bfr[4];
#pragma unroll
            for (int i = 0; i < 4; ++i) {
                int row = wm * 64 + i * 16 + (lane & 15);
                af[i] = load_frag(&As[row * 64 + (col16 ^ (row & 7)) * 8]);
            }
#pragma unroll
            for (int j = 0; j < 4; ++j) {
                int row = wn * 64 + j * 16 + (lane & 15);
                bfr[j] = load_frag(&Bs[row * 64 + (col16 ^ (row & 7)) * 8]);
            }
#pragma unroll
            for (int i = 0; i < 4; ++i)
#pragma unroll
                for (int j = 0; j < 4; ++j)
                    acc[i][j] = __builtin_amdgcn_mfma_f32_16x16x32_bf16(af[i], bfr[j], acc[i][j], 0, 0, 0);
        }
    }

    int r0 = (lane >> 4) * 4;
    int cc = lane & 15;
    int sec = blockIdx.y >> 3;               // 0=q, 1=k
    int hh = (blockIdx.y & 7) * 2 + wn;      // head 0..15
    unsigned short* dst = (sec == 0) ? qb : kb;
    float sc = (sec == 0) ? (0.125f * 1.44269504088896f) : 1.0f;  // fold softmax scale + log2e into q
#pragma unroll
    for (int i = 0; i < 4; ++i)
#pragma unroll
        for (int r = 0; r < 4; ++r) {
            float ss = 0.0f;
#pragma unroll
            for (int j = 0; j < 4; ++j) ss += acc[i][j][r] * acc[i][j][r];
            ss += __shfl_xor(ss, 1, 64);
            ss += __shfl_xor(ss, 2, 64);
            ss += __shfl_xor(ss, 4, 64);
            ss += __shfl_xor(ss, 8, 64);
            float rn = rsqrtf(ss * (1.0f / 64.0f) + 1e-6f);
            int mm = m0 + wm * 64 + i * 16 + r0 + r;
            int t = mm & 2047, b = mm >> 11;
            size_t rowb = ((size_t)((b * 16 + hh) * 2048 + t)) * 64;
#pragma unroll
            for (int j = 0; j < 2; ++j) {
                int dm = j * 16 + cc;
                float c = cost[t * 32 + dm], s_ = sint[t * 32 + dm];
                float x1 = acc[i][j][r] * rn;
                float x2 = acc[i][j + 2][r] * rn;
                dst[rowb + dm]      = f2bf((x1 * c + x2 * s_) * sc);
                dst[rowb + 32 + dm] = f2bf((x2 * c - x1 * s_) * sc);
            }
        }
}

// ---------- V GEMM with fused lerp + v1-passthrough + in-LDS transpose (grid 32 x 8) ----------
__global__ __launch_bounds__(256) void gemm_v(const unsigned short* __restrict__ A,
                                              const unsigned short* __restrict__ Bv,  // wv rows
                                              const float* __restrict__ v1,
                                              const float* __restrict__ lamb_p,
                                              unsigned short* __restrict__ vt,
                                              float* __restrict__ outv1) {
    __shared__ __align__(16) unsigned short smem[2 * 128 * 72];   // 36864B; As/Bs alias front 32KB
    unsigned short* As = smem;
    unsigned short* Bs = smem + 128 * 64;
    int tid = threadIdx.x;
    int lane = tid & 63;
    int w = tid >> 6;
    int wm = w >> 1, wn = w & 1;
    int m0 = blockIdx.x * 128;
    int n0 = blockIdx.y * 128;

    f32x4 acc[4][4] = {};

    int r8 = lane >> 3;
    int csrc = (lane & 7) ^ r8;

    for (int k0 = 0; k0 < 1024; k0 += 64) {
        __syncthreads();
#pragma unroll
        for (int c = 0; c < 4; ++c) {
            int row = 32 * w + 8 * c + r8;
            gload_lds16(&A[(size_t)(m0 + row) * 1024 + k0 + csrc * 8], &As[(32 * w + 8 * c) * 64]);
            gload_lds16(&Bv[(size_t)(n0 + row) * 1024 + k0 + csrc * 8], &Bs[(32 * w + 8 * c) * 64]);
        }
        __syncthreads();
#pragma unroll
        for (int kk = 0; kk < 2; ++kk) {
            int col16 = kk * 4 + (lane >> 4);
            bf16x8 af[4], bfr[4];
#pragma unroll
            for (int i = 0; i < 4; ++i) {
                int row = wm * 64 + i * 16 + (lane & 15);
                af[i] = load_frag(&As[row * 64 + (col16 ^ (row & 7)) * 8]);
            }
#pragma unroll
            for (int j = 0; j < 4; ++j) {
                int row = wn * 64 + j * 16 + (lane & 15);
                bfr[j] = load_frag(&Bs[row * 64 + (col16 ^ (row & 7)) * 8]);
            }
#pragma unroll
            for (int i = 0; i < 4; ++i)
#pragma unroll
                for (int j = 0; j < 4; ++j)
                    acc[i][j] = __builtin_amdgcn_mfma_f32_16x16x32_bf16(af[i], bfr[j], acc[i][j], 0, 0, 0);
        }
    }

    // lerp + v1 passthrough, write into per-head LDS tile [head][t_local 128][d 64 +pad 72]
    typedef unsigned short (*tile_t)[128][72];
    tile_t tile = reinterpret_cast<tile_t>(smem);
    int r0 = (lane >> 4) * 4;
    int cc = lane & 15;
    int hh = blockIdx.y * 2 + wn;            // head 0..15
    float lam = lamb_p[0];
    float oml = 1.0f - lam;
    __syncthreads();                         // As/Bs dead; safe to overlay
#pragma unroll
    for (int i = 0; i < 4; ++i)
#pragma unroll
        for (int r = 0; r < 4; ++r) {
            int tl = wm * 64 + i * 16 + r0 + r;      // 0..127
            int mm = m0 + tl;
            int t = mm & 2047, b = mm >> 11;
            size_t v1row = ((size_t)((b * 2048 + t) * 16 + hh)) * 64;
#pragma unroll
            for (int j = 0; j < 4; ++j) {
                int d = j * 16 + cc;
                float v1v = v1[v1row + d];
                outv1[v1row + d] = v1v;              // v1 passthrough output
                tile[wn][tl][d] = f2bf(oml * acc[i][j][r] + lam * v1v);
            }
        }
    __syncthreads();

    // transposed store: vt[bh][d][t0+..]
    int h2 = tid >> 7;                       // 0/1
    int idx = tid & 127;
    int rr2 = idx >> 2;                      // 0..31 -> d rows rr2, rr2+32
    int c2 = (idx & 3) * 8;                  // 0,8,16,24
    int hhs = blockIdx.y * 2 + h2;
    int t0 = m0 & 2047;
    int bb = m0 >> 11;
    unsigned short* dst = vt + ((size_t)(bb * 16 + hhs)) * 64 * 2048;
    unsigned short tmp[8];
#pragma unroll
    for (int tb = 0; tb < 128; tb += 32) {
#pragma unroll
        for (int j = 0; j < 8; ++j) tmp[j] = tile[h2][tb + c2 + j][rr2];
        *reinterpret_cast<int4*>(&dst[(size_t)rr2 * 2048 + t0 + tb + c2]) = *reinterpret_cast<int4*>(tmp);
#pragma unroll
        for (int j = 0; j < 8; ++j) tmp[j] = tile[h2][tb + c2 + j][rr2 + 32];
        *reinterpret_cast<int4*>(&dst[(size_t)(rr2 + 32) * 2048 + t0 + tb + c2]) = *reinterpret_cast<int4*>(tmp);
    }
}

// ---------- proj GEMM with fused kv-split combine on the A side (proven R14) ----------
__global__ __launch_bounds__(256) void gemm_proj(const unsigned short* __restrict__ pO,
                                                 const float* __restrict__ lsum,
                                                 const unsigned short* __restrict__ B,
                                                 float* __restrict__ C) {
    __shared__ __align__(16) unsigned short As[128 * 64];
    __shared__ __align__(16) unsigned short Bs[128 * 64];
    int tid = threadIdx.x;
    int lane = tid & 63;
    int w = tid >> 6;
    int wm = w >> 1, wn = w & 1;
    int m0 = blockIdx.x * 128;
    int n0 = blockIdx.y * 128;

    f32x4 acc[4][4] = {};

    int r8 = lane >> 3;
    int c8 = lane & 7;
    int csrc = c8 ^ r8;

    for (int k0 = 0; k0 < 1024; k0 += 64) {
        int h = k0 >> 6;
        __syncthreads();
#pragma unroll
        for (int c = 0; c < 4; ++c) {
            int row = 32 * w + 8 * c + r8;
            int m = m0 + row;
            int bh = ((m >> 11) << 4) + h;
            int qi = m & 2047;
            int li = bh * 2048 + qi;
            size_t pi = (size_t)li * 64 + csrc * 8;
            int4 p0 = *reinterpret_cast<const int4*>(&pO[pi]);
            int4 p1 = *reinterpret_cast<const int4*>(&pO[4194304u + pi]);
            float linv = 1.0f / (lsum[li] + lsum[65536 + li]);
            const unsigned short* u0 = reinterpret_cast<const unsigned short*>(&p0);
            const unsigned short* u1 = reinterpret_cast<const unsigned short*>(&p1);
            unsigned short tmp[8];
#pragma unroll
            for (int j = 0; j < 8; ++j) tmp[j] = f2bf((bf2f(u0[j]) + bf2f(u1[j])) * linv);
            *reinterpret_cast<int4*>(&As[row * 64 + c8 * 8]) = *reinterpret_cast<int4*>(tmp);
            gload_lds16(&B[(size_t)(n0 + row) * 1024 + k0 + csrc * 8], &Bs[(32 * w + 8 * c) * 64]);
        }
        __syncthreads();
#pragma unroll
        for (int kk = 0; kk < 2; ++kk) {
            int col16 = kk * 4 + (lane >> 4);
            bf16x8 af[4], bfr[4];
#pragma unroll
            for (int i = 0; i < 4; ++i) {
                int row = wm * 64 + i * 16 + (lane & 15);
                af[i] = load_frag(&As[row * 64 + (col16 ^ (row & 7)) * 8]);
            }
#pragma unroll
            for (int j = 0; j < 4; ++j) {
                int row = wn * 64 + j * 16 + (lane & 15);
                bfr[j] = load_frag(&Bs[row * 64 + (col16 ^ (row & 7)) * 8]);
            }
#pragma unroll
            for (int i = 0; i < 4; ++i)
#pragma unroll
                for (int j = 0; j < 4; ++j)
                    acc[i][j] = __builtin_amdgcn_mfma_f32_16x16x32_bf16(af[i], bfr[j], acc[i][j], 0, 0, 0);
        }
    }
    int r0 = (lane >> 4) * 4;
    int cc = lane & 15;
#pragma unroll
    for (int i = 0; i < 4; ++i)
#pragma unroll
        for (int j = 0; j < 4; ++j)
#pragma unroll
            for (int r = 0; r < 4; ++r) {
                size_t m = m0 + wm * 64 + i * 16 + r0 + r;
                size_t n = n0 + wn * 64 + j * 16 + cc;
                C[m * 1024 + n] = acc[i][j][r];
            }
}

// ---------- flash attention, kv-split x2, causal, swapped-QK^T 32x32 MFMA ----------
// R17: staging rebuilt as the proven GEMM staging — global_load_lds into LINEAR
// double-buffered LDS with both-sides XOR swizzle (rule #21), ONE barrier per tile
// (stage(p^1) issued before compute(p); __syncthreads' vmcnt(0) drain covers DMA).
__global__ __launch_bounds__(256) void attn(const unsigned short* __restrict__ qb,
                                            const unsigned short* __restrict__ kb,
                                            const unsigned short* __restrict__ vt,   // [bh][64][2048]
                                            unsigned short* __restrict__ pO,         // [ck][bh][2048][64] bf16
                                            float* __restrict__ lsum) {              // [ck][bh][2048] f32
    __shared__ __align__(16) unsigned short KsL[2][64 * 64];   // [buf][kv*d] linear
    __shared__ __align__(16) unsigned short VtL[2][64 * 64];   // [buf][d*kv] linear
    int tid = threadIdx.x;
    int lane = tid & 63;
    int w = tid >> 6;
    int hi = lane >> 5;
    int l31 = lane & 31;

    int bid = blockIdx.x;                    // 0..1023
    int bh = bid & 31;
    int r5 = bid >> 5;                       // 0..31
    int qt = 15 - (r5 >> 1);                 // heavy first
    int ck = r5 & 1;
    int q0 = qt * 128;
    const size_t base = (size_t)bh * 2048 * 64;
    const unsigned short* vtb = vt + (size_t)bh * 64 * 2048;
    int ktlo = ck * (qt + 1);
    int kthi = (ck + 1) * (qt + 1);          // exclusive

    bf16x8 qf[4];
    int qrow = q0 + w * 32 + l31;
#pragma unroll
    for (int kd = 0; kd < 4; ++kd)
        qf[kd] = load_frag(&qb[base + (size_t)qrow * 64 + kd * 16 + hi * 8]);

    f32x16 oacc[2] = {};
    float lrun = 0.0f;

    // staging: each wave fills rows [(w*2+i)*8, +8) per issue; lane l covers
    // row rr = (w*2+i)*8 + (l>>3), source 16B-unit (l&7)^(rr&7) (T2 involution).
    int rl = lane >> 3;              // 0..7
    int ul = lane & 7;
#define STAGE(pp, kt_)                                                                     \
    do {                                                                                   \
        _Pragma("unroll") for (int i2 = 0; i2 < 2; ++i2) {                                 \
            int rr = (w * 2 + i2) * 8 + rl;                                                \
            int cu = ul ^ (rr & 7);                                                        \
            gload_lds16(&kb[base + (size_t)((kt_) * 64 + rr) * 64 + cu * 8],               \
                        &KsL[pp][(w * 2 + i2) * 512]);                                     \
            gload_lds16(&vtb[(size_t)rr * 2048 + (kt_) * 64 + cu * 8],                     \
                        &VtL[pp][(w * 2 + i2) * 512]);                                     \
        }                                                                                  \
    } while (0)

    int qwlo = q0 + w * 32;
    int p = 0;
    STAGE(0, ktlo);
    __syncthreads();
    for (int kt = ktlo; kt < kthi; ++kt) {
        if (kt + 1 < kthi) STAGE(p ^ 1, kt + 1);

        if (kt * 64 <= qwlo + 31) {
            bool diag = (kt * 64 + 63 > qwlo);
            float rs01 = 0.0f, rs23 = 0.0f;
#pragma unroll
            for (int ntl = 0; ntl < 2; ++ntl) {
                // QK^T for this 32-kv half: m = kv, n = q
                f32x16 sacc = {};
#pragma unroll
                for (int kd = 0; kd < 4; ++kd) {
                    int R = ntl * 32 + l31;
                    bf16x8 kf = load_frag(&KsL[p][R * 64 + (((kd << 1) | hi) ^ (R & 7)) * 8]);
                    sacc = __builtin_amdgcn_mfma_f32_32x32x16_bf16(kf, qf[kd], sacc, 0, 0, 0);
                }

#pragma unroll
                for (int r = 0; r < 16; ++r) {
                    float s = sacc[r];
                    if (diag) {
                        int kvg = kt * 64 + ntl * 32 + (r & 3) + 8 * (r >> 2) + 4 * hi;
                        if (kvg > qrow) s = -3.0e38f;
                    }
                    float e = __builtin_amdgcn_exp2f(s);
                    sacc[r] = e;
                    if (r & 2) rs23 += e; else rs01 += e;
                }

                unsigned int wAa[4], wBb[4];
#pragma unroll
                for (int rr = 0; rr < 4; ++rr) {
                    wAa[rr] = packbf2(sacc[4 * rr + 0], sacc[4 * rr + 1]);
                    wBb[rr] = packbf2(sacc[4 * rr + 2], sacc[4 * rr + 3]);
                }

                // PV for this half: 2 k-slices of 16 kv; A-frag via permlane32_swap
#pragma unroll
                for (int ks2 = 0; ks2 < 2; ++ks2) {
                    int b2 = ks2 * 2;
                    auto rA = __builtin_amdgcn_permlane32_swap(wAa[b2], wAa[b2 + 1], false, false);
                    auto rB = __builtin_amdgcn_permlane32_swap(wBb[b2], wBb[b2 + 1], false, false);
                    uint4 pa;
                    pa.x = rA[0];   // kv 16ks+8hi+{0,1}
                    pa.y = rB[0];   // +{2,3}
                    pa.z = rA[1];   // +{4,5}
                    pa.w = rB[1];   // +{6,7}
                    bf16x8 paf = __builtin_bit_cast(bf16x8, pa);
                    int ks = ntl * 2 + ks2;
#pragma unroll
                    for (int dt = 0; dt < 2; ++dt) {
                        int R2 = dt * 32 + l31;
                        bf16x8 vtf = load_frag(&VtL[p][R2 * 64 + (((ks << 1) | hi) ^ (R2 & 7)) * 8]);
                        oacc[dt] = __builtin_amdgcn_mfma_f32_32x32x16_bf16(paf, vtf, oacc[dt], 0, 0, 0);
                    }
                }
            }
            float rs = rs01 + rs23;
            rs += __shfl_xor(rs, 32, 64);
            lrun += rs;
        }
        __syncthreads();   // drains staged gloads (vmcnt 0) + protects buf p for overwrite
        p ^= 1;
    }

    unsigned short* po = pO + ((size_t)ck * 4194304u);
    float* ls = lsum + ck * 65536;
#pragma unroll
    for (int r = 0; r < 16; ++r) {
        int ql = (r & 3) + 8 * (r >> 2) + 4 * hi;
        int q = q0 + w * 32 + ql;
        size_t ro = ((size_t)bh * 2048 + q) * 64;
        po[ro + l31]      = f2bf(oacc[0][r]);
        po[ro + 32 + l31] = f2bf(oacc[1][r]);
    }
    if (hi == 0) ls[bh * 2048 + q0 + w * 32 + l31] = lrun;
#undef STAGE
}

// ---------- launch ----------
extern "C" void kernel_launch(void* const* d_in, const int* in_sizes, int n_in,
                              void* d_out, int out_size, void* d_ws, size_t ws_size,
                              hipStream_t stream) {
    const float* x      = (const float*)d_in[0];   // [2,2048,1024]
    const float* v1     = (const float*)d_in[1];   // [2,2048,16,64]
    const float* w_q    = (const float*)d_in[2];
    const float* w_k    = (const float*)d_in[3];
    const float* w_v    = (const float*)d_in[4];
    const float* w_proj = (const float*)d_in[5];
    const float* lamb   = (const float*)d_in[6];
    float* out = (float*)d_out;

    char* ws = (char*)d_ws;
    unsigned short* xb      = (unsigned short*)(ws + 0);           // 8MB
    unsigned short* wall_b  = (unsigned short*)(ws + (8u  << 20)); // 8MB: [wq|wk|wv|wproj]
    unsigned short* wqkv_b  = wall_b;
    unsigned short* wv_b    = wall_b + 2u * 1048576u;
    unsigned short* wproj_b = wall_b + 3u * 1048576u;
    unsigned short* vtp     = (unsigned short*)(ws + (40u << 20)); // 8MB [bh][64][2048]
    unsigned short* qbuf    = (unsigned short*)(ws + (48u << 20)); // 8MB
    unsigned short* kbuf    = (unsigned short*)(ws + (56u << 20)); // 8MB
    float*          cost    = (float*)        (ws + (72u << 20));
    float*          sint    = (float*)        (ws + (72u << 20) + 262144);
    unsigned short* pO      = (unsigned short*)(ws + (80u << 20)); // 2 x 8MB partials (stride 4194304 elems)
    float*          lsum    = (float*)        (ws + (112u << 20)); // 2 x 256KB

    prep_bf16<<<8448, 256, 0, stream>>>(x, w_q, w_k, w_v, w_proj, xb, wall_b, cost, sint);

    gemm_qk<<<dim3(32, 16), 256, 0, stream>>>(xb, wqkv_b, cost, sint, qbuf, kbuf);
    gemm_v<<<dim3(32, 8), 256, 0, stream>>>(xb, wv_b, v1, lamb, vtp, out + 4194304);

    attn<<<1024, 256, 0, stream>>>(qbuf, kbuf, vtp, pO, lsum);

    gemm_proj<<<dim3(32, 8), 256, 0, stream>>>(pO, lsum, wproj_b, out);
}